// Round 1
// baseline (730.023 us; speedup 1.0000x reference)
//
#include <hip/hip_runtime.h>
#include <hip/hip_bf16.h>
#include <cstdint>
#include <cstddef>

// Problem constants
#define T_TOK 4096   // BATCH*SEQ
#define DM    1024   // D_MODEL
#define DF    4096   // D_FF
#define NE    8      // N_EXPERTS (TOP_K = 2)

typedef unsigned short u16;
typedef __attribute__((ext_vector_type(8))) short  short8;
typedef __attribute__((ext_vector_type(4))) float  f32x4;
typedef __attribute__((ext_vector_type(4))) unsigned short u16x4;

__device__ __forceinline__ u16 f2b(float f) {
  union { float f; uint32_t u; } v; v.f = f;
  uint32_t u = v.u;
  u += 0x7fffu + ((u >> 16) & 1u);   // round-to-nearest-even
  return (u16)(u >> 16);
}

// ---------------- elementwise fp32 -> bf16 ----------------
__global__ void cvt_x_kernel(const float* __restrict__ in, u16* __restrict__ out, int n4) {
  int i = blockIdx.x * blockDim.x + threadIdx.x;
  if (i >= n4) return;
  f32x4 v = reinterpret_cast<const f32x4*>(in)[i];
  u16x4 o;
  o.x = f2b(v.x); o.y = f2b(v.y); o.z = f2b(v.z); o.w = f2b(v.w);
  reinterpret_cast<u16x4*>(out)[i] = o;
}

// ---------------- transpose + convert: src fp32 [R][C] -> dst bf16 [C][R] ----------------
// grid (C/64, R/64, batch), block (64,4)
__global__ void transpose_cvt(const float* __restrict__ src, u16* __restrict__ dst,
                              int R, int C) {
  __shared__ float tile[64][65];
  size_t boff = (size_t)blockIdx.z * (size_t)R * (size_t)C;
  src += boff; dst += boff;
  int c0 = blockIdx.x * 64, r0 = blockIdx.y * 64;
  int tx = threadIdx.x, ty = threadIdx.y;
  for (int i = ty; i < 64; i += 4)
    tile[i][tx] = src[(size_t)(r0 + i) * C + c0 + tx];
  __syncthreads();
  for (int i = ty; i < 64; i += 4)
    dst[(size_t)(c0 + i) * R + r0 + tx] = f2b(tile[tx][i]);
}

// ---------------- gating: fp32 logits, top-2, softmax, counts ----------------
// one wave per token; block 256 = 4 tokens
__global__ void gating_kernel(const float* __restrict__ x, const float* __restrict__ Wg,
                              int* __restrict__ counts, int* __restrict__ top_e,
                              float* __restrict__ top_w) {
  int t = (blockIdx.x * blockDim.x + threadIdx.x) >> 6;
  int lane = threadIdx.x & 63;
  if (t >= T_TOK) return;
  const float* xr = x + (size_t)t * DM;
  float acc[NE];
#pragma unroll
  for (int e = 0; e < NE; ++e) acc[e] = 0.f;
  for (int d = lane; d < DM; d += 64) {
    float xv = xr[d];
    const float* wr = Wg + d * NE;
#pragma unroll
    for (int e = 0; e < NE; ++e) acc[e] += xv * wr[e];
  }
#pragma unroll
  for (int off = 32; off > 0; off >>= 1) {
#pragma unroll
    for (int e = 0; e < NE; ++e) acc[e] += __shfl_down(acc[e], off);
  }
  if (lane == 0) {
    int e0 = 0; float v0 = acc[0];
#pragma unroll
    for (int e = 1; e < NE; ++e) if (acc[e] > v0) { v0 = acc[e]; e0 = e; }
    int e1 = -1; float v1 = -3.4e38f;
#pragma unroll
    for (int e = 0; e < NE; ++e) if (e != e0 && acc[e] > v1) { v1 = acc[e]; e1 = e; }
    float s = expf(v1 - v0);              // v1 <= v0, stable
    float inv = 1.f / (1.f + s);
    top_e[t * 2] = e0; top_e[t * 2 + 1] = e1;
    top_w[t * 2] = inv; top_w[t * 2 + 1] = s * inv;
    atomicAdd(&counts[e0], 1);
    atomicAdd(&counts[e1], 1);
  }
}

__global__ void offsets_kernel(const int* __restrict__ counts, int* __restrict__ offsets,
                               int* __restrict__ cursor) {
  if (threadIdx.x == 0) {
    int s = 0;
    for (int e = 0; e < NE; ++e) { offsets[e] = s; s += counts[e]; }
    offsets[NE] = s;
  }
  if (threadIdx.x < NE) cursor[threadIdx.x] = 0;
}

__global__ void scatter_kernel(const int* __restrict__ top_e, const float* __restrict__ top_w,
                               const int* __restrict__ offsets, int* __restrict__ cursor,
                               int* __restrict__ pair_token, float* __restrict__ pair_w) {
  int t = blockIdx.x * blockDim.x + threadIdx.x;
  if (t >= T_TOK) return;
#pragma unroll
  for (int k = 0; k < 2; ++k) {
    int e = top_e[t * 2 + k];
    int slot = atomicAdd(&cursor[e], 1);
    pair_token[offsets[e] + slot] = t;
    pair_w[offsets[e] + slot] = top_w[t * 2 + k];
  }
}

// ---------------- grouped FFN GEMM ----------------
// PASS 1: H[base+r] = relu(Xb[tok] @ W1T^T + b1)   (K=1024, N=4096)
// PASS 2: Out[tok]  += w * (H[base+r] @ W2T^T + b2) (K=4096, N=1024)
// B operands pre-transposed to [N][K] so both A and B stage as row-major K-slices.
// 128x128 tile, BK=64, 256 threads (4 waves, 2x2 of 64x64), mfma 16x16x32 bf16.
template <int PASS>
__global__ __launch_bounds__(256)
void ffn_gemm(const u16* __restrict__ Xb, u16* __restrict__ H,
              const u16* __restrict__ WT, const u16* __restrict__ WsT,
              const float* __restrict__ bias_e, const float* __restrict__ bias_s,
              const int* __restrict__ counts, const int* __restrict__ offsets,
              const int* __restrict__ pair_token, const float* __restrict__ pair_w,
              float* __restrict__ Out) {
  constexpr int K = (PASS == 1) ? DM : DF;
  constexpr int N = (PASS == 1) ? DF : DM;
  const int e = blockIdx.z;
  int cnt, base;
  if (e < NE) { cnt = counts[e]; base = offsets[e]; }
  else        { cnt = T_TOK;     base = 2 * T_TOK; }   // shared expert rows live at H[8192..]
  const int row0 = blockIdx.y * 128;
  if (row0 >= cnt) return;
  const int col0 = blockIdx.x * 128;

  __shared__ alignas(16) u16 As[128][72];   // +8 pad: 144B row stride, ~2-way banks
  __shared__ alignas(16) u16 Bs[128][72];
  __shared__ int   toks[128];
  __shared__ float wrow[128];

  const int tid = threadIdx.x;
  if (tid < 128) {
    int r = row0 + tid;
    int tok = -1; float w = 0.f;
    if (r < cnt) {
      if (e < NE) { tok = pair_token[base + r]; w = pair_w[base + r]; }
      else        { tok = r;                    w = 1.f; }
    }
    toks[tid] = tok;
    wrow[tid] = w;
  }
  __syncthreads();

  const u16* Bsrc = (e < NE) ? (WT + (size_t)e * (size_t)K * N) : WsT;  // [N][K]
  const float* bias = (e < NE) ? (bias_e + (size_t)e * N) : bias_s;

  // staging: thread -> (row, 32-element half); 8x16B global loads per K-step
  const int sr = tid >> 1;
  const int sh = tid & 1;
  const u16* a_src = nullptr;
  if (PASS == 1) {
    int tok = toks[sr];
    if (tok >= 0) a_src = Xb + (size_t)tok * DM + sh * 32;
  } else {
    if (row0 + sr < cnt) a_src = H + (size_t)(base + row0 + sr) * DF + sh * 32;
  }
  const u16* b_src = Bsrc + (size_t)(col0 + sr) * K + sh * 32;

  const int wv = tid >> 6;
  const int wr = wv >> 1, wc = wv & 1;
  const int lane = tid & 63;
  const int q = lane >> 4, r16 = lane & 15;

  f32x4 acc[4][4];
#pragma unroll
  for (int i = 0; i < 4; ++i)
#pragma unroll
    for (int j = 0; j < 4; ++j) acc[i][j] = (f32x4)0.f;

  for (int k0 = 0; k0 < K; k0 += 64) {
    short8 av[4], bv[4];
#pragma unroll
    for (int j = 0; j < 4; ++j) {
      av[j] = a_src ? *reinterpret_cast<const short8*>(a_src + k0 + j * 8) : (short8)0;
      bv[j] = *reinterpret_cast<const short8*>(b_src + k0 + j * 8);
    }
    __syncthreads();   // previous iter's LDS reads complete
#pragma unroll
    for (int j = 0; j < 4; ++j) {
      *reinterpret_cast<short8*>(&As[sr][sh * 32 + j * 8]) = av[j];
      *reinterpret_cast<short8*>(&Bs[sr][sh * 32 + j * 8]) = bv[j];
    }
    __syncthreads();
#pragma unroll
    for (int ks = 0; ks < 2; ++ks) {
      short8 af[4], bf[4];
#pragma unroll
      for (int mt = 0; mt < 4; ++mt)
        af[mt] = *reinterpret_cast<const short8*>(&As[wr * 64 + mt * 16 + r16][ks * 32 + q * 8]);
#pragma unroll
      for (int nt = 0; nt < 4; ++nt)
        bf[nt] = *reinterpret_cast<const short8*>(&Bs[wc * 64 + nt * 16 + r16][ks * 32 + q * 8]);
#pragma unroll
      for (int mt = 0; mt < 4; ++mt)
#pragma unroll
        for (int nt = 0; nt < 4; ++nt)
          acc[mt][nt] = __builtin_amdgcn_mfma_f32_16x16x32_bf16(af[mt], bf[nt], acc[mt][nt], 0, 0, 0);
    }
  }

  // epilogue: C/D layout col=lane&15, row=(lane>>4)*4+reg  [verified m89/m91]
#pragma unroll
  for (int mt = 0; mt < 4; ++mt) {
    int rl = wr * 64 + mt * 16 + q * 4;
#pragma unroll
    for (int nt = 0; nt < 4; ++nt) {
      int col = col0 + wc * 64 + nt * 16 + r16;
      float bcol = bias[col];
#pragma unroll
      for (int v = 0; v < 4; ++v) {
        int r = rl + v;
        if (row0 + r >= cnt) continue;
        float val = acc[mt][nt][v] + bcol;
        if (PASS == 1) {
          val = fmaxf(val, 0.f);
          H[(size_t)(base + row0 + r) * DF + col] = f2b(val);
        } else {
          atomicAdd(Out + (size_t)toks[r] * DM + col, wrow[r] * val);
        }
      }
    }
  }
}

extern "C" void kernel_launch(void* const* d_in, const int* in_sizes, int n_in,
                              void* d_out, int out_size, void* d_ws, size_t ws_size,
                              hipStream_t stream) {
  const float* x   = (const float*)d_in[0];
  const float* Wg  = (const float*)d_in[1];
  const float* W1  = (const float*)d_in[2];
  const float* b1  = (const float*)d_in[3];
  const float* W2  = (const float*)d_in[4];
  const float* b2  = (const float*)d_in[5];
  const float* Ws1 = (const float*)d_in[6];
  const float* bs1 = (const float*)d_in[7];
  const float* Ws2 = (const float*)d_in[8];
  const float* bs2 = (const float*)d_in[9];
  float* out = (float*)d_out;

  // workspace layout (~249 MiB required)
  char* ws = (char*)d_ws;
  size_t off = 0;
  auto alloc = [&](size_t bytes) -> char* {
    char* p = ws + off;
    off = (off + bytes + 255) & ~(size_t)255;
    return p;
  };
  int*   counts     = (int*)  alloc(NE * 4);
  int*   offsets    = (int*)  alloc((NE + 1) * 4);
  int*   cursor     = (int*)  alloc(NE * 4);
  int*   top_e      = (int*)  alloc((size_t)T_TOK * 2 * 4);
  float* top_w      = (float*)alloc((size_t)T_TOK * 2 * 4);
  int*   pair_token = (int*)  alloc((size_t)T_TOK * 2 * 4);
  float* pair_w     = (float*)alloc((size_t)T_TOK * 2 * 4);
  u16*   Xb   = (u16*)alloc((size_t)T_TOK * DM * 2);
  u16*   W1T  = (u16*)alloc((size_t)NE * DM * DF * 2);   // [e][DF][DM]
  u16*   W2T  = (u16*)alloc((size_t)NE * DM * DF * 2);   // [e][DM][DF]
  u16*   Ws1T = (u16*)alloc((size_t)DM * DF * 2);        // [DF][DM]
  u16*   Ws2T = (u16*)alloc((size_t)DM * DF * 2);        // [DM][DF]
  u16*   H    = (u16*)alloc((size_t)3 * T_TOK * DF * 2); // rows: 8192 expert pairs + 4096 shared
  (void)ws_size; (void)in_sizes; (void)n_in;

  hipMemsetAsync(counts, 0, NE * 4, stream);
  hipMemsetAsync(d_out, 0, (size_t)out_size * sizeof(float), stream);

  cvt_x_kernel<<<(T_TOK * DM / 4 + 255) / 256, 256, 0, stream>>>(x, Xb, T_TOK * DM / 4);
  dim3 tb(64, 4);
  transpose_cvt<<<dim3(DF / 64, DM / 64, NE), tb, 0, stream>>>(W1, W1T, DM, DF);
  transpose_cvt<<<dim3(DM / 64, DF / 64, NE), tb, 0, stream>>>(W2, W2T, DF, DM);
  transpose_cvt<<<dim3(DF / 64, DM / 64, 1), tb, 0, stream>>>(Ws1, Ws1T, DM, DF);
  transpose_cvt<<<dim3(DM / 64, DF / 64, 1), tb, 0, stream>>>(Ws2, Ws2T, DF, DM);

  gating_kernel<<<T_TOK / 4, 256, 0, stream>>>(x, Wg, counts, top_e, top_w);
  offsets_kernel<<<1, 64, 0, stream>>>(counts, offsets, cursor);
  scatter_kernel<<<T_TOK / 256, 256, 0, stream>>>(top_e, top_w, offsets, cursor, pair_token, pair_w);

  ffn_gemm<1><<<dim3(DF / 128, T_TOK / 128, NE + 1), 256, 0, stream>>>(
      Xb, H, W1T, Ws1T, b1, bs1, counts, offsets, pair_token, pair_w, out);
  ffn_gemm<2><<<dim3(DM / 128, T_TOK / 128, NE + 1), 256, 0, stream>>>(
      Xb, H, W2T, Ws2T, b2, bs2, counts, offsets, pair_token, pair_w, out);
}